// Round 1
// baseline (888.447 us; speedup 1.0000x reference)
//
#include <hip/hip_runtime.h>

// Problem constants (from reference)
#define NV 20000
#define BSZ 80
#define CIN 16
#define NNZE 6400000
#define KDIM 1280          // B * C_IN * R_IN
#define NOUT 512           // C_OUT * R_OUT
#define MROWS 20000
static const long long AGG_ELEMS = (long long)NV * BSZ * CIN;   // 25.6M f32 = 102.4 MB

__global__ void zero_kernel(float4* __restrict__ p, long long n4) {
    long long i = (long long)blockIdx.x * blockDim.x + threadIdx.x;
    long long stride = (long long)gridDim.x * blockDim.x;
    for (; i < n4; i += stride) p[i] = make_float4(0.f, 0.f, 0.f, 0.f);
}

// lw[k*512 + o*16 + j] = weights[o*1280 + (k/80)*80 + ((t+j)%16)*5 + p], i=k%80,t=i/5,p=i%5
__global__ void build_lw_kernel(const float* __restrict__ w, float* __restrict__ lw) {
    int idx = blockIdx.x * blockDim.x + threadIdx.x;   // < 1280*512
    int k = idx >> 9;
    int n = idx & 511;
    int o = n >> 4, j = n & 15;
    int ci = k / 80;
    int i  = k % 80;
    int t  = i / 5, p = i % 5;
    int src = ci * 80 + ((t + j) & 15) * 5 + p;
    lw[idx] = w[o * KDIM + src];
}

// one thread per (edge, channel): agg[row*16+c] += val * x[col*16+c]
__global__ __launch_bounds__(256) void scatter_kernel(
        const float* __restrict__ vals, const int* __restrict__ rows,
        const int* __restrict__ cols, const float* __restrict__ x,
        float* __restrict__ agg) {
    long long idx = (long long)blockIdx.x * 256 + threadIdx.x;
    if (idx >= (long long)NNZE * 16) return;
    int e = (int)(idx >> 4);
    int c = (int)(idx & 15);
    int r  = rows[e];
    int cl = cols[e];
    float v = vals[e];
    atomicAdd(agg + ((long long)r * 16 + c), v * x[cl * 16 + c]);
}

// f32 GEMM: C[M=20000][512] = A[M][1280] * Bm[1280][512]
// 128x128 tile, BK=8, 256 threads, 8x8 per-thread microtile
__global__ __launch_bounds__(256) void gemm_kernel(
        const float* __restrict__ A, const float* __restrict__ Bm,
        float* __restrict__ C) {
    __shared__ float As[8][132];
    __shared__ float Bs[8][132];
    const int K = KDIM, N = NOUT, M = MROWS;
    int tid = threadIdx.x;
    int tx = tid & 15, ty = tid >> 4;
    int row0 = blockIdx.x * 128;
    int col0 = blockIdx.y * 128;
    int arow = tid >> 1, ak = (tid & 1) * 4;       // A: 128 rows x 8 k
    int brow = tid >> 5, bcol = (tid & 31) * 4;    // B: 8 k x 128 cols

    float acc[8][8];
#pragma unroll
    for (int i = 0; i < 8; i++)
#pragma unroll
        for (int j = 0; j < 8; j++) acc[i][j] = 0.f;

    for (int k0 = 0; k0 < K; k0 += 8) {
        int gr = row0 + arow;
        float4 av = make_float4(0.f, 0.f, 0.f, 0.f);
        if (gr < M) av = *(const float4*)(A + (long long)gr * K + k0 + ak);
        As[ak + 0][arow] = av.x;
        As[ak + 1][arow] = av.y;
        As[ak + 2][arow] = av.z;
        As[ak + 3][arow] = av.w;
        float4 bv = *(const float4*)(Bm + (long long)(k0 + brow) * N + col0 + bcol);
        *(float4*)&Bs[brow][bcol] = bv;
        __syncthreads();
#pragma unroll
        for (int kk = 0; kk < 8; kk++) {
            float a[8], b[8];
            *(float4*)&a[0] = *(const float4*)&As[kk][ty * 8];
            *(float4*)&a[4] = *(const float4*)&As[kk][ty * 8 + 4];
            *(float4*)&b[0] = *(const float4*)&Bs[kk][tx * 8];
            *(float4*)&b[4] = *(const float4*)&Bs[kk][tx * 8 + 4];
#pragma unroll
            for (int i = 0; i < 8; i++)
#pragma unroll
                for (int j = 0; j < 8; j++)
                    acc[i][j] = fmaf(a[i], b[j], acc[i][j]);
        }
        __syncthreads();
    }

#pragma unroll
    for (int i = 0; i < 8; i++) {
        int row = row0 + ty * 8 + i;
        if (row < M) {
            float4 c0 = make_float4(acc[i][0], acc[i][1], acc[i][2], acc[i][3]);
            float4 c1 = make_float4(acc[i][4], acc[i][5], acc[i][6], acc[i][7]);
            *(float4*)(C + (long long)row * N + col0 + tx * 8)     = c0;
            *(float4*)(C + (long long)row * N + col0 + tx * 8 + 4) = c1;
        }
    }
}

extern "C" void kernel_launch(void* const* d_in, const int* in_sizes, int n_in,
                              void* d_out, int out_size, void* d_ws, size_t ws_size,
                              hipStream_t stream) {
    const float* x        = (const float*)d_in[0];
    const float* weights  = (const float*)d_in[1];
    const float* conn_vals = (const float*)d_in[2];
    const int*   conn_rows = (const int*)d_in[3];
    const int*   conn_cols = (const int*)d_in[4];
    float* out = (float*)d_out;

    float* agg = (float*)d_ws;                                   // 102.4 MB
    float* lw  = (float*)((char*)d_ws + (size_t)AGG_ELEMS * 4);  // 2.6 MB

    hipLaunchKernelGGL(zero_kernel, dim3(2048), dim3(256), 0, stream,
                       (float4*)agg, AGG_ELEMS / 4);
    hipLaunchKernelGGL(build_lw_kernel, dim3((KDIM * NOUT) / 256), dim3(256), 0, stream,
                       weights, lw);
    long long total = (long long)NNZE * 16;
    hipLaunchKernelGGL(scatter_kernel, dim3((unsigned)((total + 255) / 256)), dim3(256),
                       0, stream, conn_vals, conn_rows, conn_cols, x, agg);
    hipLaunchKernelGGL(gemm_kernel, dim3((MROWS + 127) / 128, NOUT / 128), dim3(256),
                       0, stream, agg, lw, out);
}

// Round 4
// 627.517 us; speedup vs baseline: 1.4158x; 1.4158x over previous
//
#include <hip/hip_runtime.h>

#define NV 20000
#define NNZE 6400000
#define KD 1280          // K = B * C_IN * R_IN
#define ND 512           // C_OUT * R_OUT
#define MROWS 20000
#define MPAD 20096       // 157 * 128 (padded rows so GEMM staging never faults)

typedef __attribute__((ext_vector_type(8))) short short8;
typedef __attribute__((ext_vector_type(4))) float f32x4;

static const size_t AGG_ELEMS = (size_t)MPAD * KD;   // padded agg, f32

// exact RNE f32 -> bf16 (finite inputs)
static __device__ __forceinline__ unsigned short f2bf(float f) {
    unsigned int u = __float_as_uint(f);
    unsigned int r = (u + 0x7FFFu + ((u >> 16) & 1u)) >> 16;
    return (unsigned short)r;
}

__global__ void zero_kernel(float4* __restrict__ p, long long n4) {
    long long i = (long long)blockIdx.x * blockDim.x + threadIdx.x;
    long long stride = (long long)gridDim.x * blockDim.x;
    for (; i < n4; i += stride) p[i] = make_float4(0.f, 0.f, 0.f, 0.f);
}

// lwT[n][k] (bf16, n-major) where lw[k][n] = weights[o*KD + src], n = o*16+j
__global__ void build_lwT_kernel(const float* __restrict__ w, unsigned short* __restrict__ lwT) {
    int idx = blockIdx.x * blockDim.x + threadIdx.x;    // < 512*1280
    int n = idx / KD;
    int k = idx - n * KD;
    int o = n >> 4, j = n & 15;
    int ci = k / 80;
    int i  = k - ci * 80;
    int t  = i / 5, p = i - t * 5;
    int src = ci * 80 + ((t + j) & 15) * 5 + p;
    lwT[idx] = f2bf(w[o * KD + src]);
}

// one thread per (edge, channel): agg[row*16+c] += val * x[col*16+c]
// atomic-transaction-bound (~250G atomics/s); known 413us from R1
__global__ __launch_bounds__(256) void scatter_kernel(
        const float* __restrict__ vals, const int* __restrict__ rows,
        const int* __restrict__ cols, const float* __restrict__ x,
        float* __restrict__ agg) {
    long long idx = (long long)blockIdx.x * 256 + threadIdx.x;
    if (idx >= (long long)NNZE * 16) return;
    int e = (int)(idx >> 4);
    int c = (int)(idx & 15);
    int r  = rows[e];
    int cl = cols[e];
    float v = vals[e];
    atomicAdd(agg + ((long long)r << 4) + c, v * x[(cl << 4) + c]);
}

// C[M][512] = A_f32[M][1280] * lwT^T ; bf16 MFMA 16x16x32, 128x128 tile, BK=64
// A: reg-staged f32 -> cvt bf16 -> XOR-swizzled LDS.  B: global_load_lds w/
// inverse-pre-swizzled global source (linear LDS dest).  Swizzle: cb ^= (row&7)<<4.
__global__ __launch_bounds__(256) void gemm_kernel(
        const float* __restrict__ A, const unsigned short* __restrict__ lwT,
        float* __restrict__ C) {
    __shared__ __align__(16) char lds[2 * 128 * 64 * 2];   // As 16KB | Bs 16KB
    char* As = lds;
    char* Bs = lds + 128 * 64 * 2;

    int tid  = threadIdx.x;
    int lane = tid & 63;
    int wid  = tid >> 6;
    int wr = wid >> 1, wc = wid & 1;       // 2x2 waves, 64x64 each
    int m0 = blockIdx.x * 128;
    int n0 = blockIdx.y * 128;

    int l15 = lane & 15;
    int l4  = lane >> 4;

    f32x4 acc[4][4] = {};

    // A staging assignment: 2 threads per row, each covers 32 consecutive f32 (128B)
    int arow  = tid >> 1;
    int ahalf = tid & 1;
    const float* aptr = A + (size_t)(m0 + arow) * KD + ahalf * 32;
    int aswz = (arow & 7) << 4;

    for (int k0 = 0; k0 < KD; k0 += 64) {
        // --- issue A global loads (8 x dwordx4 per thread, 128B contiguous) ---
        float4 av[8];
#pragma unroll
        for (int q = 0; q < 8; q++)
            av[q] = ((const float4*)(aptr + k0))[q];

        // --- issue B global_load_lds: 16KB tile, 4 rounds x 256 threads x 16B ---
#pragma unroll
        for (int rd = 0; rd < 4; rd++) {
            int idx  = rd * 256 + tid;
            int brow = idx >> 3;               // 0..127
            int cb   = (idx & 7) * 16;         // byte within 128B row
            size_t src = (size_t)(n0 + brow) * (KD * 2) + (size_t)(k0 * 2)
                       + (size_t)(cb ^ ((brow & 7) << 4));
            __builtin_amdgcn_global_load_lds(
                (const __attribute__((address_space(1))) void*)((const char*)lwT + src),
                (__attribute__((address_space(3))) void*)(Bs + rd * 4096 + wid * 1024),
                16, 0, 0);
        }

        // --- convert A to bf16, write swizzled to LDS (4 x ds_write_b128) ---
#pragma unroll
        for (int q = 0; q < 4; q++) {
            short8 s;
            s[0] = (short)f2bf(av[2*q].x);   s[1] = (short)f2bf(av[2*q].y);
            s[2] = (short)f2bf(av[2*q].z);   s[3] = (short)f2bf(av[2*q].w);
            s[4] = (short)f2bf(av[2*q+1].x); s[5] = (short)f2bf(av[2*q+1].y);
            s[6] = (short)f2bf(av[2*q+1].z); s[7] = (short)f2bf(av[2*q+1].w);
            int cb = ahalf * 64 + q * 16;
            *(short8*)(As + arow * 128 + (cb ^ aswz)) = s;
        }

        __syncthreads();   // drains vmcnt (gload_lds) + lgkmcnt (ds_write)

        // --- compute: 2 k-subtiles x (4m x 4n) MFMA ---
#pragma unroll
        for (int ks = 0; ks < 2; ks++) {
            short8 af[4], bf[4];
            int kb = ks * 64 + l4 * 16;
#pragma unroll
            for (int m = 0; m < 4; m++) {
                int r = wr * 64 + m * 16 + l15;
                af[m] = *(const short8*)(As + r * 128 + (kb ^ ((r & 7) << 4)));
            }
#pragma unroll
            for (int n = 0; n < 4; n++) {
                int r = wc * 64 + n * 16 + l15;
                bf[n] = *(const short8*)(Bs + r * 128 + (kb ^ ((r & 7) << 4)));
            }
#pragma unroll
            for (int m = 0; m < 4; m++)
#pragma unroll
                for (int n = 0; n < 4; n++)
                    acc[m][n] = __builtin_amdgcn_mfma_f32_16x16x32_bf16(
                                    af[m], bf[n], acc[m][n], 0, 0, 0);
        }

        __syncthreads();   // all waves done reading LDS before next-iter overwrite
    }

    // --- epilogue: D col = lane&15, row = (lane>>4)*4 + reg ---
#pragma unroll
    for (int m = 0; m < 4; m++) {
        int row_b = m0 + wr * 64 + m * 16 + l4 * 4;
#pragma unroll
        for (int n = 0; n < 4; n++) {
            int col = n0 + wc * 64 + n * 16 + l15;
#pragma unroll
            for (int r = 0; r < 4; r++) {
                int row = row_b + r;
                if (row < MROWS) C[(size_t)row * ND + col] = acc[m][n][r];
            }
        }
    }
}

extern "C" void kernel_launch(void* const* d_in, const int* in_sizes, int n_in,
                              void* d_out, int out_size, void* d_ws, size_t ws_size,
                              hipStream_t stream) {
    const float* x         = (const float*)d_in[0];
    const float* weights   = (const float*)d_in[1];
    const float* conn_vals = (const float*)d_in[2];
    const int*   conn_rows = (const int*)d_in[3];
    const int*   conn_cols = (const int*)d_in[4];
    float* out = (float*)d_out;

    float*          agg = (float*)d_ws;                                   // 102.9 MB (padded)
    unsigned short* lwT = (unsigned short*)((char*)d_ws + AGG_ELEMS * 4); // 1.31 MB

    hipLaunchKernelGGL(zero_kernel, dim3(4096), dim3(256), 0, stream,
                       (float4*)agg, (long long)(AGG_ELEMS / 4));
    hipLaunchKernelGGL(build_lwT_kernel, dim3((ND * KD) / 256), dim3(256), 0, stream,
                       weights, lwT);
    long long total = (long long)NNZE * 16;
    hipLaunchKernelGGL(scatter_kernel, dim3((unsigned)((total + 255) / 256)), dim3(256),
                       0, stream, conn_vals, conn_rows, conn_cols, x, agg);
    hipLaunchKernelGGL(gemm_kernel, dim3(MPAD / 128, ND / 128), dim3(256), 0, stream,
                       agg, lwT, out);
}